// Round 12
// baseline (134.631 us; speedup 1.0000x reference)
//
#include <hip/hip_runtime.h>
#include <hip/hip_bf16.h>
#include <stdint.h>

#define B_    4
#define S_    4096
#define F_    1024
#define A_    512
#define N3_   1536
#define M_    16384

#define BM    128
#define BN    192
#define BK    32
#define NT    (F_ / BK)   // 32 K-tiles
#define LDP2  130         // Xt col-major stride (elems), 65 words (odd) -> bank-spread

typedef __attribute__((ext_vector_type(8))) __bf16 bf16x8;
typedef __attribute__((ext_vector_type(4))) float f32x4;

#define MFMA(a, b, c) __builtin_amdgcn_mfma_f32_16x16x32_bf16((a), (b), (c), 0, 0, 0)

// ---------- helpers ----------
__device__ __forceinline__ float bflo(unsigned int u) {
  union { unsigned int i; float f; } v; v.i = u << 16; return v.f;
}
__device__ __forceinline__ float bfhi(unsigned int u) {
  union { unsigned int i; float f; } v; v.i = u & 0xffff0000u; return v.f;
}
__device__ __forceinline__ float bf1(unsigned short u) {
  union { unsigned int i; float f; } v; v.i = ((unsigned int)u) << 16; return v.f;
}
__device__ __forceinline__ unsigned short bfc(float f) {
  return __builtin_bit_cast(unsigned short, __float2bfloat16(f));
}
__device__ __forceinline__ ushort4 cvt_bf4(float4 v) {
  ushort4 o;
  o.x = bfc(v.x); o.y = bfc(v.y); o.z = bfc(v.z); o.w = bfc(v.w);
  return o;
}

typedef __attribute__((address_space(3))) unsigned int lds_uint;
typedef const __attribute__((address_space(1))) unsigned int glob_uint;
__device__ __forceinline__ void lds_load16(const void* g, void* l) {
  __builtin_amdgcn_global_load_lds((glob_uint*)g, (lds_uint*)l, 16, 0, 0);
}

// ---------- K1: convert inp -> bf16 (+ column sums for mean), W[1536:3072] -> bf16 ----------
__global__ __launch_bounds__(256) void convert_mean_kernel(
    const float* __restrict__ inp, const float* __restrict__ W,
    unsigned short* __restrict__ inp_bf, unsigned short* __restrict__ w_bf,
    float* __restrict__ mu) {
  int blk = blockIdx.x;   // 512
  int t   = threadIdx.x;  // 256
  int r0  = blk * 32;
  int b   = r0 >> 12;
  float acc0 = 0.f, acc1 = 0.f, acc2 = 0.f, acc3 = 0.f;
  for (int r = 0; r < 32; r++) {
    size_t row = (size_t)(r0 + r);
    float4 v = ((const float4*)(inp + row * F_))[t];
    acc0 += v.x; acc1 += v.y; acc2 += v.z; acc3 += v.w;
    ((ushort4*)(inp_bf + row * F_))[t] = cvt_bf4(v);
  }
  atomicAdd(&mu[b * F_ + t * 4 + 0], acc0);
  atomicAdd(&mu[b * F_ + t * 4 + 1], acc1);
  atomicAdd(&mu[b * F_ + t * 4 + 2], acc2);
  atomicAdd(&mu[b * F_ + t * 4 + 3], acc3);

  const float* Wc = W + (size_t)N3_ * F_;
  const int n4 = (N3_ * F_) / 4;
  for (int i = blk * 256 + t; i < n4; i += 512 * 256) {
    ((ushort4*)w_bf)[i] = cvt_bf4(((const float4*)Wc)[i]);
  }
}

// ---------- K2: agg[b,a] = (mu[b,:]/S) . Wq[a,:] + b_q[a] ----------
__global__ void agg_kernel(const float* __restrict__ mu, const float* __restrict__ W,
                           const float* __restrict__ bias, float* __restrict__ agg) {
  int gw = blockIdx.x * 4 + (threadIdx.x >> 6);
  int lane = threadIdx.x & 63;
  int b = gw >> 9, a = gw & 511;
  const float4* wr = (const float4*)(W + (size_t)a * F_);
  const float4* mr = (const float4*)(mu + b * F_);
  float s = 0.f;
#pragma unroll
  for (int k = 0; k < 4; k++) {
    float4 wv = wr[lane + 64 * k], mv = mr[lane + 64 * k];
    s += wv.x * mv.x + wv.y * mv.y + wv.z * mv.z + wv.w * mv.w;
  }
  for (int off = 32; off; off >>= 1) s += __shfl_down(s, off);
  if (lane == 0) agg[b * A_ + a] = s * (1.f / S_) + bias[a];
}

// ---------- K3: v[b,f] += sum_{a in chunk} agg[b,a]*Wk[a,f] ----------
__global__ void v_kernel(const float* __restrict__ agg, const float* __restrict__ W,
                         float* __restrict__ v) {
  int fc = blockIdx.x;  // 0..3
  int ac = blockIdx.y;  // 0..7
  int t = threadIdx.x;
  int f = fc * 256 + t;
  const float* Wk = W + (size_t)A_ * F_;
  float s0 = 0.f, s1 = 0.f, s2 = 0.f, s3 = 0.f;
  int a0 = ac * 64;
  for (int a = a0; a < a0 + 64; a++) {
    float wv = Wk[(size_t)a * F_ + f];
    s0 += agg[a] * wv;
    s1 += agg[A_ + a] * wv;
    s2 += agg[2 * A_ + a] * wv;
    s3 += agg[3 * A_ + a] * wv;
  }
  atomicAdd(&v[f], s0);
  atomicAdd(&v[F_ + f], s1);
  atomicAdd(&v[2 * F_ + f], s2);
  atomicAdd(&v[3 * F_ + f], s3);
}

// ---------- K4: fused scores + online-softmax + weighted-sum; chunk staged in LDS ----------
__global__ __launch_bounds__(256) void scores_u_kernel(
    const unsigned short* __restrict__ inp_bf, const float* __restrict__ v,
    float* __restrict__ uP, float* __restrict__ mlzl) {
  extern __shared__ char sulds[];
  unsigned short* xl = (unsigned short*)sulds;   // 64 rows x 1024 bf16 = 128 KB
  float* sc  = (float*)(sulds + 131072);         // 64
  float* wsl = sc + 64;                          // 64

  int blk = blockIdx.x;            // 0..255
  int b = blk >> 6, ch = blk & 63;
  int s0 = ch * 64;
  int t = threadIdx.x, lane = t & 63, wv = t >> 6;   // 4 waves

  const float4* vp = (const float4*)(v + b * F_);
  float4 va0 = vp[lane * 2], va1 = vp[lane * 2 + 1];
  float4 vb0 = vp[(lane + 64) * 2], vb1 = vp[(lane + 64) * 2 + 1];
#pragma unroll
  for (int i = 0; i < 16; i++) {
    int r = wv * 16 + i;
    const uint4* ip = (const uint4*)(inp_bf + ((size_t)(b * S_ + s0 + r)) * F_);
    uint4 x0 = ip[lane], x1 = ip[lane + 64];
    *(uint4*)&xl[r * 1024 + lane * 8]       = x0;
    *(uint4*)&xl[r * 1024 + 512 + lane * 8] = x1;
    float s = bflo(x0.x) * va0.x + bfhi(x0.x) * va0.y + bflo(x0.y) * va0.z + bfhi(x0.y) * va0.w +
              bflo(x0.z) * va1.x + bfhi(x0.z) * va1.y + bflo(x0.w) * va1.z + bfhi(x0.w) * va1.w +
              bflo(x1.x) * vb0.x + bfhi(x1.x) * vb0.y + bflo(x1.y) * vb0.z + bfhi(x1.y) * vb0.w +
              bflo(x1.z) * vb1.x + bfhi(x1.z) * vb1.y + bflo(x1.w) * vb1.z + bfhi(x1.w) * vb1.w;
    for (int off = 32; off; off >>= 1) s += __shfl_down(s, off);
    if (lane == 0) sc[r] = s;
  }
  __syncthreads();

  float m = -1e30f;
#pragma unroll
  for (int i = 0; i < 64; i++) m = fmaxf(m, sc[i]);
  if (t < 64) wsl[t] = __expf(sc[t] - m);
  __syncthreads();

  {
    const unsigned short* xp = xl + t * 4;
    float a0 = 0.f, a1 = 0.f, a2 = 0.f, a3 = 0.f;
    for (int s = 0; s < 64; s++) {
      uint2 xv = *(const uint2*)&xp[s * 1024];
      float w = wsl[s];
      a0 += w * bflo(xv.x); a1 += w * bfhi(xv.x);
      a2 += w * bflo(xv.y); a3 += w * bfhi(xv.y);
    }
    float4 o; o.x = a0; o.y = a1; o.z = a2; o.w = a3;
    *(float4*)&uP[(size_t)blk * 1024 + t * 4] = o;
  }
  if (t == 0) {
    float Z = 0.f;
#pragma unroll
    for (int i = 0; i < 64; i++) Z += wsl[i];
    mlzl[blk * 2] = m; mlzl[blk * 2 + 1] = Z;
  }
}

// ---------- K5: finalize u ----------
__global__ void ufin_kernel(const float* __restrict__ uP, const float* __restrict__ mlzl,
                            float* __restrict__ u) {
  int b = blockIdx.x >> 2, fs = blockIdx.x & 3;   // 16 blocks
  int f = fs * 256 + threadIdx.x;
  float M = -1e30f;
#pragma unroll
  for (int i = 0; i < 64; i++) M = fmaxf(M, mlzl[(b * 64 + i) * 2]);
  float Z = 0.f;
#pragma unroll
  for (int i = 0; i < 64; i++) Z += __expf(mlzl[(b * 64 + i) * 2] - M) * mlzl[(b * 64 + i) * 2 + 1];
  float acc = 0.f;
  for (int ch = 0; ch < 64; ch++) {
    float sc = __expf(mlzl[(b * 64 + ch) * 2] - M);
    acc += sc * uP[(size_t)(b * 64 + ch) * 1024 + f];
  }
  u[b * F_ + f] = acc / Z;
}

// ---------- K6: ctx[b,a] = u[b,:] . Wv[a,:] + b_v[a] ----------
__global__ void ctx_kernel(const float* __restrict__ u, const float* __restrict__ W,
                           const float* __restrict__ bias, float* __restrict__ ctx) {
  int gw = blockIdx.x * 4 + (threadIdx.x >> 6);
  int lane = threadIdx.x & 63;
  int b = gw >> 9, a = gw & 511;
  const float4* wr = (const float4*)(W + (size_t)(2 * A_ + a) * F_);
  const float4* ur = (const float4*)(u + b * F_);
  float s = 0.f;
#pragma unroll
  for (int k = 0; k < 4; k++) {
    float4 wv = wr[lane + 64 * k], uv = ur[lane + 64 * k];
    s += wv.x * uv.x + wv.y * uv.y + wv.z * uv.z + wv.w * uv.w;
  }
  for (int off = 32; off; off >>= 1) s += __shfl_down(s, off);
  if (lane == 0) ctx[b * A_ + a] = s + bias[2 * A_ + a];
}

// ---------- K7: fused GEMM + final.  128x192 tile, BK=32, 2 blocks/CU ----------
__global__ __launch_bounds__(512, 4) void gemm_fused(
    const __hip_bfloat16* __restrict__ Abf,
    const __hip_bfloat16* __restrict__ Wbf,
    const float* __restrict__ biasP,   // bias + 1536
    const float* __restrict__ ctx,
    float* __restrict__ out,
    unsigned short* __restrict__ sideLoc,
    float* __restrict__ sideGO) {
  extern __shared__ unsigned short smem[];
  unsigned short* ldsA = smem;           // 2 bufs x 4096 elems (128x32)
  unsigned short* ldsB = smem + 8192;    // 2 bufs x 6144 elems (192x32)
  unsigned short* Xt   = smem;           // epilogue alias: [192 cols][130 rows]
  float* segred = (float*)((char*)smem + 192 * LDP2 * 2);  // 2 x 64 f32

  int bid = blockIdx.x;
  int swz = (bid & 7) * 128 + (bid >> 3);  // 1024 blocks, 8 XCDs, bijective
  int mb = swz >> 3;   // 0..127
  int nb = swz & 7;    // 0..7

  int tid  = threadIdx.x;
  int lane = tid & 63;
  int wv   = tid >> 6;       // 0..7
  int wm   = wv >> 2;        // 0..1 : 64-row slice
  int wn   = wv & 3;         // 0..3 : 48-col slice
  int lo   = lane & 15, hi = lane >> 4;

  // read swizzle: source k-slot hi lives at LDS slot hi^(row&3); row&3 == lo&3
  int rsw = ((hi ^ (lo & 3)) << 3);

  const __hip_bfloat16* Ab = Abf + (size_t)mb * BM * F_;

  // staging: A unit u=tid (row=tid>>2, slot=tid&3); B unit0 u=tid, unit1 u=512+tid (tid<256)
  int srow  = tid >> 2;                          // 0..127
  int sslot = (((tid & 3) ^ (srow & 3)) << 3);   // swizzled source elem offset
  size_t gB0 = (size_t)((srow >> 6) * 512 + nb * 64 + (srow & 63)) * F_;
  size_t gB1 = (size_t)(1024 + nb * 64 + (srow & 63)) * F_;   // rows 128..191 -> out strip

  f32x4 acc[4][3];
#pragma unroll
  for (int i = 0; i < 4; i++)
#pragma unroll
    for (int j = 0; j < 3; j++) acc[i][j] = (f32x4){0.f, 0.f, 0.f, 0.f};

  int aBase = (wm * 64 + lo) * 32;
  int bBase = (wn * 48 + lo) * 32;

#define STAGE(kt_, buf_)                                                                   \
  {                                                                                        \
    int kof_ = (kt_) * BK;                                                                 \
    lds_load16(Ab + (size_t)srow * F_ + kof_ + sslot, ldsA + (buf_) * 4096 + wv * 512);    \
    lds_load16(Wbf + gB0 + kof_ + sslot,              ldsB + (buf_) * 6144 + wv * 512);    \
    if (wv < 4)                                                                            \
      lds_load16(Wbf + gB1 + kof_ + sslot, ldsB + (buf_) * 6144 + 4096 + wv * 512);        \
  }

  // prologue: stage tile 0
  STAGE(0, 0);

  for (int kt = 0; kt < NT; ++kt) {
    int c = kt & 1, nx = c ^ 1;
    bool pf = (kt + 1 < NT);
    const unsigned short* la = ldsA + c * 4096;
    const unsigned short* lb = ldsB + c * 6144;

    __builtin_amdgcn_s_barrier();        // all waves done reading buf nx (prev tile)
    if (pf) {
      STAGE(kt + 1, nx);
      if (wv < 4) asm volatile("s_waitcnt vmcnt(3)" ::: "memory");  // own kt loads landed
      else        asm volatile("s_waitcnt vmcnt(2)" ::: "memory");
    } else {
      asm volatile("s_waitcnt vmcnt(0)" ::: "memory");
    }
    __builtin_amdgcn_s_barrier();        // buf c visible to all waves

    bf16x8 af[4], bfr[3];
#pragma unroll
    for (int fi = 0; fi < 4; fi++) af[fi] = *(const bf16x8*)&la[aBase + fi * 512 + rsw];
#pragma unroll
    for (int fj = 0; fj < 3; fj++) bfr[fj] = *(const bf16x8*)&lb[bBase + fj * 512 + rsw];
    asm volatile("s_waitcnt lgkmcnt(0)" ::: "memory");
    __builtin_amdgcn_sched_barrier(0);
    __builtin_amdgcn_s_setprio(1);
#pragma unroll
    for (int fi = 0; fi < 4; fi++)
#pragma unroll
      for (int fj = 0; fj < 3; fj++)
        acc[fi][fj] = MFMA(af[fi], bfr[fj], acc[fi][fj]);
    __builtin_amdgcn_s_setprio(0);
  }
#undef STAGE

  __syncthreads();   // all waves done with staging LDS before Xt overwrite

  // ---------------- epilogue ----------------
  // acc (+bias) -> Xt col-major bf16. C/D: col=lane&15, row=(lane>>4)*4+reg.
  float bias_r[3];
#pragma unroll
  for (int fj = 0; fj < 3; fj++) {
    int cl = wn * 48 + fj * 16 + lo;
    bias_r[fj] = biasP[(cl >> 6) * 512 + nb * 64 + (cl & 63)];
  }
#pragma unroll
  for (int fi = 0; fi < 4; fi++) {
#pragma unroll
    for (int fj = 0; fj < 3; fj++) {
      int cl = wn * 48 + fj * 16 + lo;
      int r  = wm * 64 + fi * 16 + hi * 4;
      float v0 = acc[fi][fj][0] + bias_r[fj];
      float v1 = acc[fi][fj][1] + bias_r[fj];
      float v2 = acc[fi][fj][2] + bias_r[fj];
      float v3 = acc[fi][fj][3] + bias_r[fj];
      unsigned int u01 = (unsigned int)bfc(v0) | ((unsigned int)bfc(v1) << 16);
      unsigned int u23 = (unsigned int)bfc(v2) | ((unsigned int)bfc(v3) << 16);
      *(unsigned int*)&Xt[cl * LDP2 + r]     = u01;
      *(unsigned int*)&Xt[cl * LDP2 + r + 2] = u23;
    }
  }
  __syncthreads();

  // segment maxes: seg strip = Xt cols 0..63; 2 segments of 64 rows
  if (tid < 128) {
    int seg = tid >> 6, c = tid & 63;
    int base = c * LDP2 + seg * 64;
    float m = -1e30f;
#pragma unroll
    for (int k = 0; k < 32; k++) {
      unsigned int uu = *(const unsigned int*)&Xt[base + 2 * k];
      m = fmaxf(m, fmaxf(bflo(uu), bfhi(uu)));
    }
    segred[seg * 64 + c] = m;
  }
  __syncthreads();

  // final combine: wave wv owns rows wv*16..+15, lane = col c (0..63)
  {
    int c  = lane;
    int r0 = wv * 16;
    int b  = mb >> 5;
    int gcol = nb * 64 + c;
    float g = ctx[b * 512 + gcol] + segred[(r0 >> 6) * 64 + c];
    int lbase = (64 + c) * LDP2;
    int obase = (128 + c) * LDP2;
    float lw0 = bf1(Xt[lbase + max(r0 - 2, 0)]);
    float lw1 = bf1(Xt[lbase + max(r0 - 1, 0)]);
    float lw2 = bf1(Xt[lbase + r0]);
    float lw3 = bf1(Xt[lbase + r0 + 1]);
    size_t obase_g = ((size_t)(mb * BM + r0)) * 512 + gcol;
#pragma unroll
    for (int j = 0; j < 16; j++) {
      int rn = min(r0 + j + 2, 127);
      float lw4 = bf1(Xt[lbase + rn]);
      float lm = fmaxf(fmaxf(fmaxf(lw0, lw1), fmaxf(lw2, lw3)), lw4);
      float o = bf1(Xt[obase + r0 + j]);
      out[obase_g + (size_t)j * 512] = g * o + lm;
      lw0 = lw1; lw1 = lw2; lw2 = lw3; lw3 = lw4;
    }
  }

  // side buffers for tile-boundary loc-window fixup (rows 0,1,126,127)
  if (tid < 256) {
    int rsel = tid >> 6, c = tid & 63;
    int r = (rsel < 2) ? rsel : (124 + rsel);   // 0,1,126,127
    int b = mb >> 5;
    float g = ctx[b * 512 + nb * 64 + c] + segred[(r >> 6) * 64 + c];
    float o = bf1(Xt[(128 + c) * LDP2 + r]);
    int gr = mb * 4 + rsel;
    sideLoc[gr * 512 + nb * 64 + c] = Xt[(64 + c) * LDP2 + r];
    sideGO[gr * 512 + nb * 64 + c]  = g * o;
  }
}

// ---------- K8: fixup for loc windows crossing 128-row tile boundaries ----------
__global__ void fixup_kernel(const unsigned short* __restrict__ sideLoc,
                             const float* __restrict__ sideGO,
                             float* __restrict__ out) {
  int rb = blockIdx.x;      // 0..127
  int tb = rb & 31;         // tile index within b (32 tiles of 128 rows)
  int t = threadIdx.x;      // 256
  int rsel = t >> 6, cq = t & 63;
#pragma unroll
  for (int k = 0; k < 8; k++) {
    int c = cq * 8 + k;
    float miss;
    int rl;
    if (rsel == 0) {
      if (tb == 0) continue;
      miss = fmaxf(bf1(sideLoc[((rb - 1) * 4 + 2) * 512 + c]),
                   bf1(sideLoc[((rb - 1) * 4 + 3) * 512 + c]));
      rl = 0;
    } else if (rsel == 1) {
      if (tb == 0) continue;
      miss = bf1(sideLoc[((rb - 1) * 4 + 3) * 512 + c]);
      rl = 1;
    } else if (rsel == 2) {
      if (tb == 31) continue;
      miss = bf1(sideLoc[((rb + 1) * 4 + 0) * 512 + c]);
      rl = 126;
    } else {
      if (tb == 31) continue;
      miss = fmaxf(bf1(sideLoc[((rb + 1) * 4 + 0) * 512 + c]),
                   bf1(sideLoc[((rb + 1) * 4 + 1) * 512 + c]));
      rl = 127;
    }
    size_t oi = ((size_t)rb * BM + rl) * 512 + c;
    float cand = sideGO[(rb * 4 + rsel) * 512 + c] + miss;
    out[oi] = fmaxf(out[oi], cand);
  }
}

// ---------- launch ----------
extern "C" void kernel_launch(void* const* d_in, const int* in_sizes, int n_in,
                              void* d_out, int out_size, void* d_ws, size_t ws_size,
                              hipStream_t stream) {
  const float* inp  = (const float*)d_in[0];
  const float* W    = (const float*)d_in[1];
  const float* bias = (const float*)d_in[2];
  float* out = (float*)d_out;
  char* ws = (char*)d_ws;

  const size_t INP_OFF  = 0;                   // bf16 inp: 33,554,432
  const size_t W_OFF    = 33554432;            // bf16 W[1536:3072]: 3,145,728
  const size_t MU_OFF   = 36700160;            // f32 mu: 16,384
  const size_t U_OFF    = MU_OFF + 16384;      // f32 u: 16,384
  const size_t V_OFF    = U_OFF + 16384;       // f32 v: 16,384
  const size_t AGG_OFF  = V_OFF + 16384;       // f32 agg: 8,192
  const size_t CTX_OFF  = AGG_OFF + 8192;      // f32 ctx: 8,192
  const size_t SL_OFF   = CTX_OFF + 8192;      // sideLoc bf16: 512*512*2 = 524,288
  const size_t SG_OFF   = SL_OFF + 524288;     // sideGO f32: 512*512*4 = 1,048,576
  const size_t UP_OFF   = SG_OFF + 1048576;    // f32 uP: 1,048,576
  const size_t ML_OFF   = UP_OFF + 1048576;    // f32 mlzl: 2,048

  unsigned short* inp_bf = (unsigned short*)(ws + INP_OFF);
  unsigned short* w_bf   = (unsigned short*)(ws + W_OFF);
  float* mu     = (float*)(ws + MU_OFF);
  float* u      = (float*)(ws + U_OFF);
  float* v      = (float*)(ws + V_OFF);
  float* agg    = (float*)(ws + AGG_OFF);
  float* ctx    = (float*)(ws + CTX_OFF);
  unsigned short* sideLoc = (unsigned short*)(ws + SL_OFF);
  float* sideGO = (float*)(ws + SG_OFF);
  float* uP     = (float*)(ws + UP_OFF);
  float* mlzl   = (float*)(ws + ML_OFF);

  hipFuncSetAttribute(reinterpret_cast<const void*>(gemm_fused),
                      hipFuncAttributeMaxDynamicSharedMemorySize, 50432);
  hipFuncSetAttribute(reinterpret_cast<const void*>(scores_u_kernel),
                      hipFuncAttributeMaxDynamicSharedMemorySize, 131584);

  hipMemsetAsync(ws + MU_OFF, 0, 3 * 16384, stream);  // zero mu, u, v
  convert_mean_kernel<<<512, 256, 0, stream>>>(inp, W, inp_bf, w_bf, mu);
  agg_kernel<<<512, 256, 0, stream>>>(mu, W, bias, agg);
  v_kernel<<<dim3(4, 8), 256, 0, stream>>>(agg, W, v);
  scores_u_kernel<<<256, 256, 131584, stream>>>(inp_bf, v, uP, mlzl);
  ufin_kernel<<<16, 256, 0, stream>>>(uP, mlzl, u);
  ctx_kernel<<<512, 256, 0, stream>>>(u, W, bias, ctx);
  gemm_fused<<<1024, 512, 50432, stream>>>((const __hip_bfloat16*)inp_bf,
                                           (const __hip_bfloat16*)w_bf,
                                           bias + 3 * A_, ctx, out, sideLoc, sideGO);
  fixup_kernel<<<128, 256, 0, stream>>>(sideLoc, sideGO, out);
}

// Round 13
// 127.044 us; speedup vs baseline: 1.0597x; 1.0597x over previous
//
#include <hip/hip_runtime.h>
#include <hip/hip_bf16.h>
#include <stdint.h>

#define B_    4
#define S_    4096
#define F_    1024
#define A_    512
#define N3_   1536
#define M_    16384

#define BM    128
#define BK    64
#define NT    (F_ / BK)   // 16 K-tiles
#define LDP2  130         // Xt col-major stride (elems)

typedef __attribute__((ext_vector_type(8))) __bf16 bf16x8;
typedef __attribute__((ext_vector_type(4))) float f32x4;

#define MFMA(a, b, c) __builtin_amdgcn_mfma_f32_16x16x32_bf16((a), (b), (c), 0, 0, 0)

// ---------- helpers ----------
__device__ __forceinline__ float bflo(unsigned int u) {
  union { unsigned int i; float f; } v; v.i = u << 16; return v.f;
}
__device__ __forceinline__ float bfhi(unsigned int u) {
  union { unsigned int i; float f; } v; v.i = u & 0xffff0000u; return v.f;
}
__device__ __forceinline__ float bf1(unsigned short u) {
  union { unsigned int i; float f; } v; v.i = ((unsigned int)u) << 16; return v.f;
}
__device__ __forceinline__ unsigned short bfc(float f) {
  return __builtin_bit_cast(unsigned short, __float2bfloat16(f));
}
__device__ __forceinline__ ushort4 cvt_bf4(float4 v) {
  ushort4 o;
  o.x = bfc(v.x); o.y = bfc(v.y); o.z = bfc(v.z); o.w = bfc(v.w);
  return o;
}

typedef __attribute__((address_space(3))) unsigned int lds_uint;
typedef const __attribute__((address_space(1))) unsigned int glob_uint;
__device__ __forceinline__ void lds_load16(const void* g, void* l) {
  __builtin_amdgcn_global_load_lds((glob_uint*)g, (lds_uint*)l, 16, 0, 0);
}

// ---------- K1: convert inp -> bf16 (+ column sums for mean), W[1536:3072] -> bf16 ----------
__global__ __launch_bounds__(256) void convert_mean_kernel(
    const float* __restrict__ inp, const float* __restrict__ W,
    unsigned short* __restrict__ inp_bf, unsigned short* __restrict__ w_bf,
    float* __restrict__ mu) {
  int blk = blockIdx.x;   // 512
  int t   = threadIdx.x;  // 256
  int r0  = blk * 32;
  int b   = r0 >> 12;
  float acc0 = 0.f, acc1 = 0.f, acc2 = 0.f, acc3 = 0.f;
  for (int r = 0; r < 32; r++) {
    size_t row = (size_t)(r0 + r);
    float4 v = ((const float4*)(inp + row * F_))[t];
    acc0 += v.x; acc1 += v.y; acc2 += v.z; acc3 += v.w;
    ((ushort4*)(inp_bf + row * F_))[t] = cvt_bf4(v);
  }
  atomicAdd(&mu[b * F_ + t * 4 + 0], acc0);
  atomicAdd(&mu[b * F_ + t * 4 + 1], acc1);
  atomicAdd(&mu[b * F_ + t * 4 + 2], acc2);
  atomicAdd(&mu[b * F_ + t * 4 + 3], acc3);

  const float* Wc = W + (size_t)N3_ * F_;
  const int n4 = (N3_ * F_) / 4;
  for (int i = blk * 256 + t; i < n4; i += 512 * 256) {
    ((ushort4*)w_bf)[i] = cvt_bf4(((const float4*)Wc)[i]);
  }
}

// ---------- K2: agg[b,a] = (mu[b,:]/S) . Wq[a,:] + b_q[a] ----------
__global__ void agg_kernel(const float* __restrict__ mu, const float* __restrict__ W,
                           const float* __restrict__ bias, float* __restrict__ agg) {
  int gw = blockIdx.x * 4 + (threadIdx.x >> 6);
  int lane = threadIdx.x & 63;
  int b = gw >> 9, a = gw & 511;
  const float4* wr = (const float4*)(W + (size_t)a * F_);
  const float4* mr = (const float4*)(mu + b * F_);
  float s = 0.f;
#pragma unroll
  for (int k = 0; k < 4; k++) {
    float4 wv = wr[lane + 64 * k], mv = mr[lane + 64 * k];
    s += wv.x * mv.x + wv.y * mv.y + wv.z * mv.z + wv.w * mv.w;
  }
  for (int off = 32; off; off >>= 1) s += __shfl_down(s, off);
  if (lane == 0) agg[b * A_ + a] = s * (1.f / S_) + bias[a];
}

// ---------- K3: v[b,f] += sum_{a in chunk} agg[b,a]*Wk[a,f] ----------
__global__ void v_kernel(const float* __restrict__ agg, const float* __restrict__ W,
                         float* __restrict__ v) {
  int fc = blockIdx.x;  // 0..3
  int ac = blockIdx.y;  // 0..7
  int t = threadIdx.x;
  int f = fc * 256 + t;
  const float* Wk = W + (size_t)A_ * F_;
  float s0 = 0.f, s1 = 0.f, s2 = 0.f, s3 = 0.f;
  int a0 = ac * 64;
  for (int a = a0; a < a0 + 64; a++) {
    float wv = Wk[(size_t)a * F_ + f];
    s0 += agg[a] * wv;
    s1 += agg[A_ + a] * wv;
    s2 += agg[2 * A_ + a] * wv;
    s3 += agg[3 * A_ + a] * wv;
  }
  atomicAdd(&v[f], s0);
  atomicAdd(&v[F_ + f], s1);
  atomicAdd(&v[2 * F_ + f], s2);
  atomicAdd(&v[3 * F_ + f], s3);
}

// ---------- K4: fused scores + online-softmax + weighted-sum partials ----------
__global__ __launch_bounds__(256) void scores_u_kernel(
    const unsigned short* __restrict__ inp_bf, const float* __restrict__ v,
    float* __restrict__ uP, float* __restrict__ mlzl) {
  int blk = blockIdx.x;            // 0..255
  int b = blk >> 6, ch = blk & 63;
  int s0 = ch * 64;
  int t = threadIdx.x, lane = t & 63, wv = t >> 6;   // 4 waves
  __shared__ float sc[64];
  __shared__ float wsl[64];

  const float4* vp = (const float4*)(v + b * F_);
  float4 va0 = vp[lane * 2], va1 = vp[lane * 2 + 1];
  float4 vb0 = vp[(lane + 64) * 2], vb1 = vp[(lane + 64) * 2 + 1];
#pragma unroll
  for (int i = 0; i < 16; i++) {
    int r = wv * 16 + i;
    const uint4* ip = (const uint4*)(inp_bf + ((size_t)(b * S_ + s0 + r)) * F_);
    uint4 x0 = ip[lane], x1 = ip[lane + 64];
    float s = bflo(x0.x) * va0.x + bfhi(x0.x) * va0.y + bflo(x0.y) * va0.z + bfhi(x0.y) * va0.w +
              bflo(x0.z) * va1.x + bfhi(x0.z) * va1.y + bflo(x0.w) * va1.z + bfhi(x0.w) * va1.w +
              bflo(x1.x) * vb0.x + bfhi(x1.x) * vb0.y + bflo(x1.y) * vb0.z + bfhi(x1.y) * vb0.w +
              bflo(x1.z) * vb1.x + bfhi(x1.z) * vb1.y + bflo(x1.w) * vb1.z + bfhi(x1.w) * vb1.w;
    for (int off = 32; off; off >>= 1) s += __shfl_down(s, off);
    if (lane == 0) sc[r] = s;
  }
  __syncthreads();

  float m = -1e30f;
#pragma unroll
  for (int i = 0; i < 64; i++) m = fmaxf(m, sc[i]);
  if (t < 64) wsl[t] = __expf(sc[t] - m);
  __syncthreads();

  {
    const unsigned short* xp = inp_bf + ((size_t)(b * S_ + s0)) * F_ + t * 4;
    float a0 = 0.f, a1 = 0.f, a2 = 0.f, a3 = 0.f;
    for (int s = 0; s < 64; s++) {
      uint2 xv = *(const uint2*)&xp[(size_t)s * F_];
      float w = wsl[s];
      a0 += w * bflo(xv.x); a1 += w * bfhi(xv.x);
      a2 += w * bflo(xv.y); a3 += w * bfhi(xv.y);
    }
    float4 o; o.x = a0; o.y = a1; o.z = a2; o.w = a3;
    *(float4*)&uP[(size_t)blk * 1024 + t * 4] = o;
  }
  if (t == 0) {
    float Z = 0.f;
#pragma unroll
    for (int i = 0; i < 64; i++) Z += wsl[i];
    mlzl[blk * 2] = m; mlzl[blk * 2 + 1] = Z;
  }
}

// ---------- K5: finalize u ----------
__global__ void ufin_kernel(const float* __restrict__ uP, const float* __restrict__ mlzl,
                            float* __restrict__ u) {
  int b = blockIdx.x >> 2, fs = blockIdx.x & 3;   // 16 blocks
  int f = fs * 256 + threadIdx.x;
  float M = -1e30f;
#pragma unroll
  for (int i = 0; i < 64; i++) M = fmaxf(M, mlzl[(b * 64 + i) * 2]);
  float Z = 0.f;
#pragma unroll
  for (int i = 0; i < 64; i++) Z += __expf(mlzl[(b * 64 + i) * 2] - M) * mlzl[(b * 64 + i) * 2 + 1];
  float acc = 0.f;
  for (int ch = 0; ch < 64; ch++) {
    float sc = __expf(mlzl[(b * 64 + ch) * 2] - M);
    acc += sc * uP[(size_t)(b * 64 + ch) * 1024 + f];
  }
  u[b * F_ + f] = acc / Z;
}

// ---------- K6: ctx[b,a] = u[b,:] . Wv[a,:] + b_v[a] ----------
__global__ void ctx_kernel(const float* __restrict__ u, const float* __restrict__ W,
                           const float* __restrict__ bias, float* __restrict__ ctx) {
  int gw = blockIdx.x * 4 + (threadIdx.x >> 6);
  int lane = threadIdx.x & 63;
  int b = gw >> 9, a = gw & 511;
  const float4* wr = (const float4*)(W + (size_t)(2 * A_ + a) * F_);
  const float4* ur = (const float4*)(u + b * F_);
  float s = 0.f;
#pragma unroll
  for (int k = 0; k < 4; k++) {
    float4 wv = wr[lane + 64 * k], uv = ur[lane + 64 * k];
    s += wv.x * uv.x + wv.y * uv.y + wv.z * uv.z + wv.w * uv.w;
  }
  for (int off = 32; off; off >>= 1) s += __shfl_down(s, off);
  if (lane == 0) ctx[b * A_ + a] = s + bias[2 * A_ + a];
}

// ---------- K7: fused GEMM + final. 128x192 tile, BK=64, R9 loop, 2 blocks/CU ----------
__global__ __launch_bounds__(512, 4) void gemm_fused(
    const __hip_bfloat16* __restrict__ Abf,
    const __hip_bfloat16* __restrict__ Wbf,
    const float* __restrict__ biasP,   // bias + 1536
    const float* __restrict__ ctx,
    float* __restrict__ out,
    unsigned short* __restrict__ sideLoc,
    float* __restrict__ sideGO) {
  extern __shared__ unsigned short smem[];
  unsigned short* ldsA = smem;            // 2 bufs x 8192 elems (128x64)
  unsigned short* ldsB = smem + 16384;    // 2 bufs x 12288 elems (192x64)
  unsigned short* Xt   = smem;            // epilogue alias: [192 cols][130 rows]
  float* segred = (float*)((char*)smem + 192 * LDP2 * 2);  // 2 x 64 f32

  int bid = blockIdx.x;
  int swz = (bid & 7) * 128 + (bid >> 3);  // 1024 blocks, 8 XCDs, bijective
  int mb = swz >> 3;   // 0..127
  int nb = swz & 7;    // 0..7

  int tid  = threadIdx.x;
  int lane = tid & 63;
  int wv   = tid >> 6;       // 0..7
  int wm   = wv >> 2;        // 0..1 : 64-row slice
  int wn   = wv & 3;         // 0..3 : 48-col slice
  int lo   = lane & 15, hi = lane >> 4, sw = lane & 7;

  int bir0 = (((hi * 16)      ^ (sw << 4)) >> 1);
  int bir1 = (((64 + hi * 16) ^ (sw << 4)) >> 1);

  const __hip_bfloat16* Ab = Abf + (size_t)mb * BM * F_;

  int srow = tid >> 3;                       // 0..63
  int sel  = ((tid & 7) ^ (srow & 7)) * 8;
  int ldst = wv * 512;

  f32x4 acc[4][3];
#pragma unroll
  for (int i = 0; i < 4; i++)
#pragma unroll
    for (int j = 0; j < 3; j++) acc[i][j] = (f32x4){0.f, 0.f, 0.f, 0.f};

  int aBase = (wm * 64 + lo) * 64;
  int bBase = (wn * 48 + lo) * 64;

#define STG_A(kt_, buf_, r_)                                                              \
  lds_load16(Ab + (size_t)((r_) * 64 + srow) * F_ + (kt_) * BK + sel,                     \
             ldsA + (buf_) * 8192 + (r_) * 4096 + ldst)
#define STG_B(kt_, buf_, q_)                                                              \
  lds_load16(Wbf + (size_t)((q_) * 512 + nb * 64 + srow) * F_ + (kt_) * BK + sel,         \
             ldsB + (buf_) * 12288 + (q_) * 4096 + ldst)

  bf16x8 af[4][2], b0[2], b1[2], b2[2];

  // prologue: stage tile 0 (5 loads), wait, read A + b0 of tile 0
  STG_A(0, 0, 0); STG_A(0, 0, 1);
  STG_B(0, 0, 0); STG_B(0, 0, 1); STG_B(0, 0, 2);
  asm volatile("s_waitcnt vmcnt(0)" ::: "memory");
  __builtin_amdgcn_s_barrier();
#pragma unroll
  for (int i = 0; i < 4; i++) {
    af[i][0] = *(const bf16x8*)&ldsA[aBase + i * 1024 + bir0];
    af[i][1] = *(const bf16x8*)&ldsA[aBase + i * 1024 + bir1];
  }
  b0[0] = *(const bf16x8*)&ldsB[bBase + bir0];
  b0[1] = *(const bf16x8*)&ldsB[bBase + bir1];

  for (int kt = 0; kt < NT; ++kt) {
    int c = kt & 1, nx = c ^ 1;
    bool pf = (kt + 1 < NT);
    const unsigned short* lb  = ldsB + c * 12288;
    const unsigned short* lan = ldsA + nx * 8192;
    const unsigned short* lbn = ldsB + nx * 12288;

    // ---- phase 0: stage next A; MFMA A x b0; issue b1 reads; barrier
    if (pf) { STG_A(kt + 1, nx, 0); STG_A(kt + 1, nx, 1); }
    asm volatile("s_waitcnt lgkmcnt(0)" ::: "memory");
    __builtin_amdgcn_sched_barrier(0);
    __builtin_amdgcn_s_setprio(1);
#pragma unroll
    for (int i = 0; i < 4; i++) {
      acc[i][0] = MFMA(af[i][0], b0[0], acc[i][0]);
      acc[i][0] = MFMA(af[i][1], b0[1], acc[i][0]);
    }
    __builtin_amdgcn_s_setprio(0);
    b1[0] = *(const bf16x8*)&lb[bBase + 1024 + bir0];
    b1[1] = *(const bf16x8*)&lb[bBase + 1024 + bir1];
    __builtin_amdgcn_s_barrier();

    // ---- phase 1: stage next B; MFMA A x b1; issue b2 reads; barrier
    if (pf) { STG_B(kt + 1, nx, 0); STG_B(kt + 1, nx, 1); STG_B(kt + 1, nx, 2); }
    asm volatile("s_waitcnt lgkmcnt(0)" ::: "memory");
    __builtin_amdgcn_sched_barrier(0);
    __builtin_amdgcn_s_setprio(1);
#pragma unroll
    for (int i = 0; i < 4; i++) {
      acc[i][1] = MFMA(af[i][0], b1[0], acc[i][1]);
      acc[i][1] = MFMA(af[i][1], b1[1], acc[i][1]);
    }
    __builtin_amdgcn_s_setprio(0);
    b2[0] = *(const bf16x8*)&lb[bBase + 2048 + bir0];
    b2[1] = *(const bf16x8*)&lb[bBase + 2048 + bir1];
    __builtin_amdgcn_s_barrier();

    // ---- phase 2: MFMA A x b2; vmcnt; barrier; read next tile's A + b0
    asm volatile("s_waitcnt lgkmcnt(0)" ::: "memory");
    __builtin_amdgcn_sched_barrier(0);
    __builtin_amdgcn_s_setprio(1);
#pragma unroll
    for (int i = 0; i < 4; i++) {
      acc[i][2] = MFMA(af[i][0], b2[0], acc[i][2]);
      acc[i][2] = MFMA(af[i][1], b2[1], acc[i][2]);
    }
    __builtin_amdgcn_s_setprio(0);
    if (pf) asm volatile("s_waitcnt vmcnt(0)" ::: "memory");
    __builtin_amdgcn_s_barrier();
    if (pf) {
#pragma unroll
      for (int i = 0; i < 4; i++) {
        af[i][0] = *(const bf16x8*)&lan[aBase + i * 1024 + bir0];
        af[i][1] = *(const bf16x8*)&lan[aBase + i * 1024 + bir1];
      }
      b0[0] = *(const bf16x8*)&lbn[bBase + bir0];
      b0[1] = *(const bf16x8*)&lbn[bBase + bir1];
    }
  }
#undef STG_A
#undef STG_B

  __syncthreads();   // all staging reads done before Xt overwrite

  // ---------------- epilogue ----------------
  float bias_r[3];
#pragma unroll
  for (int fj = 0; fj < 3; fj++) {
    int cl = wn * 48 + fj * 16 + lo;
    bias_r[fj] = biasP[(cl >> 6) * 512 + nb * 64 + (cl & 63)];
  }
#pragma unroll
  for (int fi = 0; fi < 4; fi++) {
#pragma unroll
    for (int fj = 0; fj < 3; fj++) {
      int cl = wn * 48 + fj * 16 + lo;
      int r  = wm * 64 + fi * 16 + hi * 4;
      float v0 = acc[fi][fj][0] + bias_r[fj];
      float v1 = acc[fi][fj][1] + bias_r[fj];
      float v2 = acc[fi][fj][2] + bias_r[fj];
      float v3 = acc[fi][fj][3] + bias_r[fj];
      unsigned int u01 = (unsigned int)bfc(v0) | ((unsigned int)bfc(v1) << 16);
      unsigned int u23 = (unsigned int)bfc(v2) | ((unsigned int)bfc(v3) << 16);
      *(unsigned int*)&Xt[cl * LDP2 + r]     = u01;
      *(unsigned int*)&Xt[cl * LDP2 + r + 2] = u23;
    }
  }
  __syncthreads();

  // segment maxes: seg strip = Xt cols 0..63; 2 segments of 64 rows
  if (tid < 128) {
    int seg = tid >> 6, c = tid & 63;
    int base = c * LDP2 + seg * 64;
    float m = -1e30f;
#pragma unroll
    for (int k = 0; k < 32; k++) {
      unsigned int uu = *(const unsigned int*)&Xt[base + 2 * k];
      m = fmaxf(m, fmaxf(bflo(uu), bfhi(uu)));
    }
    segred[seg * 64 + c] = m;
  }
  __syncthreads();

  // final combine: wave wv owns rows wv*16..+15, lane = col c (0..63)
  {
    int c  = lane;
    int r0 = wv * 16;
    int b  = mb >> 5;
    int gcol = nb * 64 + c;
    float g = ctx[b * 512 + gcol] + segred[(r0 >> 6) * 64 + c];
    int lbase = (64 + c) * LDP2;
    int obase = (128 + c) * LDP2;
    float lw0 = bf1(Xt[lbase + max(r0 - 2, 0)]);
    float lw1 = bf1(Xt[lbase + max(r0 - 1, 0)]);
    float lw2 = bf1(Xt[lbase + r0]);
    float lw3 = bf1(Xt[lbase + r0 + 1]);
    size_t obase_g = ((size_t)(mb * BM + r0)) * 512 + gcol;
#pragma unroll
    for (int j = 0; j < 16; j++) {
      int rn = min(r0 + j + 2, 127);
      float lw4 = bf1(Xt[lbase + rn]);
      float lm = fmaxf(fmaxf(fmaxf(lw0, lw1), fmaxf(lw2, lw3)), lw4);
      float o = bf1(Xt[obase + r0 + j]);
      out[obase_g + (size_t)j * 512] = g * o + lm;
      lw0 = lw1; lw1 = lw2; lw2 = lw3; lw3 = lw4;
    }
  }

  // side buffers for tile-boundary loc-window fixup (rows 0,1,126,127)
  if (tid < 256) {
    int rsel = tid >> 6, c = tid & 63;
    int r = (rsel < 2) ? rsel : (124 + rsel);   // 0,1,126,127
    int b = mb >> 5;
    float g = ctx[b * 512 + nb * 64 + c] + segred[(r >> 6) * 64 + c];
    float o = bf1(Xt[(128 + c) * LDP2 + r]);
    int gr = mb * 4 + rsel;
    sideLoc[gr * 512 + nb * 64 + c] = Xt[(64 + c) * LDP2 + r];
    sideGO[gr * 512 + nb * 64 + c]  = g * o;
  }
}

// ---------- K8: fixup for loc windows crossing 128-row tile boundaries ----------
__global__ void fixup_kernel(const unsigned short* __restrict__ sideLoc,
                             const float* __restrict__ sideGO,
                             float* __restrict__ out) {
  int rb = blockIdx.x;      // 0..127
  int tb = rb & 31;         // tile index within b (32 tiles of 128 rows)
  int t = threadIdx.x;      // 256
  int rsel = t >> 6, cq = t & 63;
#pragma unroll
  for (int k = 0; k < 8; k++) {
    int c = cq * 8 + k;
    float miss;
    int rl;
    if (rsel == 0) {
      if (tb == 0) continue;
      miss = fmaxf(bf1(sideLoc[((rb - 1) * 4 + 2) * 512 + c]),
                   bf1(sideLoc[((rb - 1) * 4 + 3) * 512 + c]));
      rl = 0;
    } else if (rsel == 1) {
      if (tb == 0) continue;
      miss = bf1(sideLoc[((rb - 1) * 4 + 3) * 512 + c]);
      rl = 1;
    } else if (rsel == 2) {
      if (tb == 31) continue;
      miss = bf1(sideLoc[((rb + 1) * 4 + 0) * 512 + c]);
      rl = 126;
    } else {
      if (tb == 31) continue;
      miss = fmaxf(bf1(sideLoc[((rb + 1) * 4 + 0) * 512 + c]),
                   bf1(sideLoc[((rb + 1) * 4 + 1) * 512 + c]));
      rl = 127;
    }
    size_t oi = ((size_t)rb * BM + rl) * 512 + c;
    float cand = sideGO[(rb * 4 + rsel) * 512 + c] + miss;
    out[oi] = fmaxf(out[oi], cand);
  }
}

// ---------- launch ----------
extern "C" void kernel_launch(void* const* d_in, const int* in_sizes, int n_in,
                              void* d_out, int out_size, void* d_ws, size_t ws_size,
                              hipStream_t stream) {
  const float* inp  = (const float*)d_in[0];
  const float* W    = (const float*)d_in[1];
  const float* bias = (const float*)d_in[2];
  float* out = (float*)d_out;
  char* ws = (char*)d_ws;

  const size_t INP_OFF  = 0;                   // bf16 inp: 33,554,432
  const size_t W_OFF    = 33554432;            // bf16 W[1536:3072]: 3,145,728
  const size_t MU_OFF   = 36700160;            // f32 mu: 16,384
  const size_t U_OFF    = MU_OFF + 16384;      // f32 u: 16,384
  const size_t V_OFF    = U_OFF + 16384;       // f32 v: 16,384
  const size_t AGG_OFF  = V_OFF + 16384;       // f32 agg: 8,192
  const size_t CTX_OFF  = AGG_OFF + 8192;      // f32 ctx: 8,192
  const size_t SL_OFF   = CTX_OFF + 8192;      // sideLoc bf16: 524,288
  const size_t SG_OFF   = SL_OFF + 524288;     // sideGO f32: 1,048,576
  const size_t UP_OFF   = SG_OFF + 1048576;    // f32 uP: 1,048,576
  const size_t ML_OFF   = UP_OFF + 1048576;    // f32 mlzl: 2,048

  unsigned short* inp_bf = (unsigned short*)(ws + INP_OFF);
  unsigned short* w_bf   = (unsigned short*)(ws + W_OFF);
  float* mu     = (float*)(ws + MU_OFF);
  float* u      = (float*)(ws + U_OFF);
  float* v      = (float*)(ws + V_OFF);
  float* agg    = (float*)(ws + AGG_OFF);
  float* ctx    = (float*)(ws + CTX_OFF);
  unsigned short* sideLoc = (unsigned short*)(ws + SL_OFF);
  float* sideGO = (float*)(ws + SG_OFF);
  float* uP     = (float*)(ws + UP_OFF);
  float* mlzl   = (float*)(ws + ML_OFF);

  hipFuncSetAttribute(reinterpret_cast<const void*>(gemm_fused),
                      hipFuncAttributeMaxDynamicSharedMemorySize, 81920);

  hipMemsetAsync(ws + MU_OFF, 0, 3 * 16384, stream);  // zero mu, u, v
  convert_mean_kernel<<<512, 256, 0, stream>>>(inp, W, inp_bf, w_bf, mu);
  agg_kernel<<<512, 256, 0, stream>>>(mu, W, bias, agg);
  v_kernel<<<dim3(4, 8), 256, 0, stream>>>(agg, W, v);
  scores_u_kernel<<<256, 256, 0, stream>>>(inp_bf, v, uP, mlzl);
  ufin_kernel<<<16, 256, 0, stream>>>(uP, mlzl, u);
  ctx_kernel<<<512, 256, 0, stream>>>(u, W, bias, ctx);
  gemm_fused<<<1024, 512, 81920, stream>>>((const __hip_bfloat16*)inp_bf,
                                           (const __hip_bfloat16*)w_bf,
                                           bias + 3 * A_, ctx, out, sideLoc, sideGO);
  fixup_kernel<<<128, 256, 0, stream>>>(sideLoc, sideGO, out);
}